// Round 17
// baseline (336.666 us; speedup 1.0000x reference)
//
#include <hip/hip_runtime.h>
#include <cstdint>
#include <cstddef>

typedef __attribute__((ext_vector_type(8))) short short8;
typedef __attribute__((ext_vector_type(8))) unsigned short ushort8;
typedef __attribute__((ext_vector_type(4))) float f32x4;

#define AS1Q const __attribute__((address_space(1)))
#define AS3Q __attribute__((address_space(3)))

constexpr int T_N = 60, IN_N = 520, MOE_RAW_N = 512, MOE_IN_N = 992;
constexpr int HID_N = 752, E_N = 8;
constexpr int K2_N = 6016;            // 8*752
constexpr int KA_N = 1024;            // padded Xm row length (992 -> 1024)
constexpr int SPLITK = 20;
constexpr int PN = 768;               // Y1 / P row pitch (layer-2 path)
constexpr int NTAIL = 240;            // tail kernel grid (<=256: co-resident)

static __device__ __forceinline__ unsigned short f2bf(float f) {
  unsigned int u = __float_as_uint(f);
  return (unsigned short)((u + 0x7fffu + ((u >> 16) & 1u)) >> 16);   // RNE
}
static __device__ __forceinline__ float sigf(float x) {
  return __fdividef(1.f, 1.f + __expf(-x));
}
static __device__ __forceinline__ float tanh_fast(float x) {
  return 2.f * __fdividef(1.f, 1.f + __expf(-2.f * x)) - 1.f;
}

// DPP row-rotate by R within the 16-lane row (pure VALU — no LDS pipe).
template<int R>
static __device__ __forceinline__ float rotf(float v) {
  return __int_as_float(__builtin_amdgcn_update_dpp(
      0, __float_as_int(v), 0x120 | R, 0xF, 0xF, true));
}
static __device__ __forceinline__ void rot8(float (&d)[8], float v) {
  d[0] = v;
  d[1] = rotf<1>(v); d[2] = rotf<2>(v); d[3] = rotf<3>(v);
  d[4] = rotf<4>(v); d[5] = rotf<5>(v); d[6] = rotf<6>(v); d[7] = rotf<7>(v);
}

// ---------------------------------------------------------------------------
// Grid barrier for an all-resident grid (NTAIL blocks, 1 block/CU).
// Release: threadfence + agent-scope RMW (L2 writeback). Acquire: per-wave
// agent-scope spin load (L2 invalidate on the observing wave's CU).
// ---------------------------------------------------------------------------
static __device__ __forceinline__ void grid_bar(unsigned* bar, unsigned target) {
  __syncthreads();
  if (threadIdx.x == 0) {
    __threadfence();
    __hip_atomic_fetch_add(bar, 1u, __ATOMIC_RELEASE, __HIP_MEMORY_SCOPE_AGENT);
  }
  if ((threadIdx.x & 63) == 0) {
    while (__hip_atomic_load(bar, __ATOMIC_ACQUIRE, __HIP_MEMORY_SCOPE_AGENT) < target)
      __builtin_amdgcn_s_sleep(2);
  }
  __syncthreads();
}

// ---------------------------------------------------------------------------
// xm_prep: Xm_bf16[b][ (i ^ (b&7)<<3) ] = bf16(Xm[b,i]), rows padded to 1024.
// Also zeroes the tail kernel's barrier counter (replay-safe).
// ---------------------------------------------------------------------------
__global__ __launch_bounds__(256)
void xm_prep(const float* __restrict__ X, unsigned short* __restrict__ XmBf,
             unsigned* __restrict__ bar)
{
  if (blockIdx.x == 0 && blockIdx.y == 0 && threadIdx.x == 0) *bar = 0u;
  const int i = blockIdx.x * 256 + threadIdx.x;   // grid.x=4 -> 0..1023
  const int b = blockIdx.y;
  const float* Xb = X + (size_t)b * (T_N * IN_N);
  float v = 0.f;
  if (i < MOE_RAW_N) {
    v = Xb[(T_N - 1) * IN_N + i];
  } else if (i < MOE_IN_N) {
    const int q = i - MOE_RAW_N;
    v = Xb[(q >> 3) * IN_N + MOE_RAW_N + (q & 7)];
  }
  XmBf[(size_t)b * KA_N + (i ^ ((b & 7) << 3))] = f2bf(v);
}

// ---------------------------------------------------------------------------
// FUSED: GRU (blocks 0..15, LDS-resident weights — R11-proven) +
// expert-separated layer-1 GEMM (blocks 16..207). Verbatim from R11.
// ---------------------------------------------------------------------------
__global__ __launch_bounds__(256, 1)
void fused_gru_gemm1(const float* __restrict__ X,
                     const float* __restrict__ Wih0, const float* __restrict__ Whh0,
                     const float* __restrict__ bih0, const float* __restrict__ bhh0,
                     const float* __restrict__ Wih1, const float* __restrict__ Whh1,
                     const float* __restrict__ bih1, const float* __restrict__ bhh1,
                     const unsigned short* __restrict__ XmBf,
                     const float* __restrict__ w1,
                     float* __restrict__ Y1, float* __restrict__ Omega)
{
  __shared__ union SM {
    struct { unsigned short Al[2][256][64]; unsigned short Bl[2][64][64]; } g; // 80 KB
    struct { float xl[T_N][256]; float wl[12][8][8]; } r;                      // 63 KB
  } sm;

  const int tid  = threadIdx.x;
  const int lane = tid & 63;
  const int wave = tid >> 6;

  if (blockIdx.x < 16) {
    // ================= GRU branch: 16 samples per block =================
    const int j = tid & 7;
    const int b = blockIdx.x * 16 + (tid >> 4);

    const float* xsrc = X + (size_t)b * (T_N * IN_N) + MOE_RAW_N + j;
#pragma unroll
    for (int t = 0; t < T_N; ++t) {
      __builtin_amdgcn_global_load_lds((AS1Q unsigned int*)(xsrc + t * IN_N),
                                       (AS3Q unsigned int*)&sm.r.xl[t][wave * 64], 4, 0, 0);
    }

    const int got = __builtin_amdgcn_update_dpp(0, j, 0x121, 0xF, 0xF, true);
    const bool plus = (got == ((j + 1) & 7));

    // gather rotation-ordered weights into LDS: wl[mat*3+gate][j][r]
    if (tid < 64) {
      const int fj = tid >> 3, fr = tid & 7;
      const int idx = plus ? ((fj + fr) & 7) : ((fj - fr) & 7);
      const float* Wm[4] = {Wih0, Whh0, Wih1, Whh1};
#pragma unroll
      for (int mat = 0; mat < 4; ++mat)
#pragma unroll
        for (int gg = 0; gg < 3; ++gg)
          sm.r.wl[mat * 3 + gg][fj][fr] = Wm[mat][(gg * 8 + fj) * 8 + idx];
    }

    const float br0 = bih0[j] + bhh0[j], bz0 = bih0[8 + j] + bhh0[8 + j];
    const float bin0 = bih0[16 + j],     bhn0 = bhh0[16 + j];
    const float br1 = bih1[j] + bhh1[j], bz1 = bih1[8 + j] + bhh1[8 + j];
    const float bin1 = bih1[16 + j],     bhn1 = bhh1[16 + j];

    __syncthreads();   // xl (vmcnt) + wl (lgkmcnt) ready

    float h1 = 0.f, h2 = 0.f;
    float xcur = sm.r.xl[0][tid];

    auto dot8 = [&](int m, const float (&rv)[8], float& accA, float& accB) {
      const f32x4 w0 = *(const f32x4*)&sm.r.wl[m][j][0];
      const f32x4 w1v = *(const f32x4*)&sm.r.wl[m][j][4];
#pragma unroll
      for (int q = 0; q < 4; ++q) { accA += w0[q] * rv[q]; accB += w1v[q] * rv[4 + q]; }
    };

#pragma unroll 1
    for (int t = 0; t <= T_N; ++t) {   // 61 iterations (software pipeline)
      const float xnext = sm.r.xl[(t + 1 < T_N) ? t + 1 : T_N - 1][tid];

      float rx[8];  rot8(rx, xcur);
      float rh1[8]; rot8(rh1, h1);
      float rh2[8]; rot8(rh2, h2);

      float grA = br0, gzA = bz0, gnA = bin0, hnA = bhn0;
      float grB = 0.f, gzB = 0.f, gnB = 0.f, hnB = 0.f;
      dot8(0, rx, grA, grB); dot8(1, rx, gzA, gzB); dot8(2, rx, gnA, gnB);
      dot8(3, rh1, grA, grB); dot8(4, rh1, gzA, gzB); dot8(5, rh1, hnA, hnB);
      float h1n;
      {
        const float r0 = sigf(grA + grB), z0 = sigf(gzA + gzB);
        const float n0 = tanh_fast((gnA + gnB) + r0 * (hnA + hnB));
        h1n = (1.f - z0) * n0 + z0 * h1;
      }

      float grA1 = br1, gzA1 = bz1, gnA1 = bin1, hnA1 = bhn1;
      float grB1 = 0.f, gzB1 = 0.f, gnB1 = 0.f, hnB1 = 0.f;
      dot8(6, rh1, grA1, grB1); dot8(7, rh1, gzA1, gzB1); dot8(8, rh1, gnA1, gnB1);
      dot8(9, rh2, grA1, grB1); dot8(10, rh2, gzA1, gzB1); dot8(11, rh2, hnA1, hnB1);
      float h2n;
      {
        const float r1 = sigf(grA1 + grB1), z1 = sigf(gzA1 + gzB1);
        const float n1 = tanh_fast((gnA1 + gnB1) + r1 * (hnA1 + hnB1));
        h2n = (1.f - z1) * n1 + z1 * h2;
      }

      h1 = h1n;
      h2 = (t == 0) ? 0.f : h2n;
      xcur = xnext;
    }

    float rv[8]; rot8(rv, h2);
    float m = rv[0];
#pragma unroll
    for (int r = 1; r < 8; ++r) m = fmaxf(m, rv[r]);
    const float ej = __expf(h2 - m);
    float re[8]; rot8(re, ej);
    float sden = 0.f;
#pragma unroll
    for (int r = 0; r < 8; ++r) sden += re[r];
    if (!(tid & 8)) Omega[b * 8 + j] = __fdividef(ej, sden);
    return;
  }

  // ================= GEMM branch: Y1[sp][e] = Xm @ w1_e =================
  const int bid = blockIdx.x - 16;           // 0..191
  const int sp  = bid / 96;                  // 0..1
  const int rr0 = bid - sp * 96;
  const int e   = rr0 & 7;
  const int nt  = rr0 >> 3;                  // 0..11
  const int n0  = nt * 64;
  const int kt0 = sp * 8, kt1 = kt0 + 8;

  const int r15 = lane & 15, hi4 = lane >> 4, r7 = lane & 7;

  const unsigned short* Abase = XmBf + (size_t)(wave * 64 + (lane >> 3)) * KA_N + (lane & 7) * 8;
  const int bn = lane;
  const int kq = wave;
  const bool nvalid = (n0 + bn) < HID_N;
  const float* Bbase = w1 + ((size_t)e * MOE_IN_N + kq * 16) * HID_N + (n0 + bn);

  f32x4 acc[4][4];
  const f32x4 zero4 = {0.f, 0.f, 0.f, 0.f};
#pragma unroll
  for (int mi = 0; mi < 4; ++mi)
#pragma unroll
    for (int ni = 0; ni < 4; ++ni) acc[mi][ni] = zero4;

  auto stage = [&](int bufi, int kt) {
    const unsigned short* ga = Abase + kt * 64;
#pragma unroll
    for (int it = 0; it < 8; ++it) {
      __builtin_amdgcn_global_load_lds(
          (AS1Q unsigned int*)(ga + (size_t)it * 8 * KA_N),
          (AS3Q unsigned int*)&sm.g.Al[bufi][wave * 64 + it * 8][0],
          16, 0, 0);
    }
    const int kbase = kt * 64 + kq * 16;
    const float* gb = Bbase + (size_t)kt * 64 * HID_N;
    float v[16];
#pragma unroll
    for (int jj = 0; jj < 16; ++jj)
      v[jj] = (nvalid && (kbase + jj) < MOE_IN_N) ? gb[(size_t)jj * HID_N] : 0.f;
    ushort8 p0, p1;
#pragma unroll
    for (int jj = 0; jj < 8; ++jj) { p0[jj] = f2bf(v[jj]); p1[jj] = f2bf(v[jj + 8]); }
    const int sl0 = ((kq * 2) ^ (bn & 7)) * 8;
    const int sl1 = ((kq * 2 + 1) ^ (bn & 7)) * 8;
    *(ushort8*)&sm.g.Bl[bufi][bn][sl0] = p0;
    *(ushort8*)&sm.g.Bl[bufi][bn][sl1] = p1;
  };

  auto compute = [&](int bufi) {
#pragma unroll
    for (int ki = 0; ki < 2; ++ki) {
      const int ch = ((ki * 4 + hi4) ^ r7) * 8;
      short8 af[4], bfv[4];
#pragma unroll
      for (int mi = 0; mi < 4; ++mi)
        af[mi] = *(const short8*)&sm.g.Al[bufi][wave * 64 + mi * 16 + r15][ch];
#pragma unroll
      for (int ni = 0; ni < 4; ++ni)
        bfv[ni] = *(const short8*)&sm.g.Bl[bufi][ni * 16 + r15][ch];
#pragma unroll
      for (int mi = 0; mi < 4; ++mi)
#pragma unroll
        for (int ni = 0; ni < 4; ++ni)
          acc[mi][ni] = __builtin_amdgcn_mfma_f32_16x16x32_bf16(af[mi], bfv[ni], acc[mi][ni], 0, 0, 0);
    }
  };

  stage(0, kt0);
  __syncthreads();
  int buf = 0;
  for (int kt = kt0; kt < kt1; ++kt) {
    if (kt + 1 < kt1) stage(buf ^ 1, kt + 1);
    compute(buf);
    __syncthreads();
    buf ^= 1;
  }

  float* Pp = Y1 + ((size_t)(sp * 8 + e) * 256) * PN + n0;
#pragma unroll
  for (int mi = 0; mi < 4; ++mi) {
    const int row = wave * 64 + mi * 16 + hi4 * 4;
#pragma unroll
    for (int ni = 0; ni < 4; ++ni) {
#pragma unroll
      for (int rq = 0; rq < 4; ++rq)
        Pp[(size_t)(row + rq) * PN + ni * 16 + r15] = acc[mi][ni][rq];
    }
  }
}

// ---------------------------------------------------------------------------
// Shared-memory type + split-K GEMM body for the tail kernel (R8/R11-proven
// gemm_splitk relocated into a __device__ function).
// ---------------------------------------------------------------------------
struct SMg { unsigned short Al[2][256][64]; unsigned short Bl[2][64][64]; };  // 80 KB

static __device__ __forceinline__
void gemm_body(SMg& sm, const unsigned short* __restrict__ A,
               const float* __restrict__ Bw, float* __restrict__ P,
               int K, int N, int NPAD, int nt, int sp)
{
  const int tid = threadIdx.x;
  const int lane = tid & 63;
  const int wave = tid >> 6;
  const int n0 = nt * 64;
  const int KT = K >> 6;
  const int kt0 = (KT * sp) / SPLITK;
  const int kt1 = (KT * (sp + 1)) / SPLITK;

  const int r15 = lane & 15, hi4 = lane >> 4, r7 = lane & 7;

  const unsigned short* Abase = A + (size_t)(wave * 64 + (lane >> 3)) * K + (lane & 7) * 8;
  const int bn = lane;
  const int kq = wave;
  const bool nvalid = (n0 + bn) < N;
  const float* Bbase = Bw + (size_t)(kq * 16) * N + (n0 + bn);

  f32x4 acc[4][4];
  const f32x4 zero4 = {0.f, 0.f, 0.f, 0.f};
#pragma unroll
  for (int mi = 0; mi < 4; ++mi)
#pragma unroll
    for (int ni = 0; ni < 4; ++ni) acc[mi][ni] = zero4;

  auto stage = [&](int bufi, int kt) {
    const unsigned short* ga = Abase + kt * 64;
#pragma unroll
    for (int it = 0; it < 8; ++it) {
      __builtin_amdgcn_global_load_lds(
          (AS1Q unsigned int*)(ga + (size_t)it * 8 * K),
          (AS3Q unsigned int*)&sm.Al[bufi][wave * 64 + it * 8][0],
          16, 0, 0);
    }
    const float* gb = Bbase + (size_t)kt * 64 * N;
    float v[16];
#pragma unroll
    for (int jj = 0; jj < 16; ++jj) v[jj] = nvalid ? gb[(size_t)jj * N] : 0.f;
    ushort8 p0, p1;
#pragma unroll
    for (int jj = 0; jj < 8; ++jj) { p0[jj] = f2bf(v[jj]); p1[jj] = f2bf(v[jj + 8]); }
    const int sl0 = ((kq * 2) ^ (bn & 7)) * 8;
    const int sl1 = ((kq * 2 + 1) ^ (bn & 7)) * 8;
    *(ushort8*)&sm.Bl[bufi][bn][sl0] = p0;
    *(ushort8*)&sm.Bl[bufi][bn][sl1] = p1;
  };

  auto compute = [&](int bufi) {
#pragma unroll
    for (int ki = 0; ki < 2; ++ki) {
      const int ch = ((ki * 4 + hi4) ^ r7) * 8;
      short8 af[4], bfv[4];
#pragma unroll
      for (int mi = 0; mi < 4; ++mi)
        af[mi] = *(const short8*)&sm.Al[bufi][wave * 64 + mi * 16 + r15][ch];
#pragma unroll
      for (int ni = 0; ni < 4; ++ni)
        bfv[ni] = *(const short8*)&sm.Bl[bufi][ni * 16 + r15][ch];
#pragma unroll
      for (int mi = 0; mi < 4; ++mi)
#pragma unroll
        for (int ni = 0; ni < 4; ++ni)
          acc[mi][ni] = __builtin_amdgcn_mfma_f32_16x16x32_bf16(af[mi], bfv[ni], acc[mi][ni], 0, 0, 0);
    }
  };

  stage(0, kt0);
  __syncthreads();
  int buf = 0;
  for (int kt = kt0; kt < kt1; ++kt) {
    if (kt + 1 < kt1) stage(buf ^ 1, kt + 1);
    compute(buf);
    __syncthreads();
    buf ^= 1;
  }

  float* Pp = P + (size_t)sp * 256 * NPAD + n0;
#pragma unroll
  for (int mi = 0; mi < 4; ++mi) {
    const int row = wave * 64 + mi * 16 + hi4 * 4;
#pragma unroll
    for (int ni = 0; ni < 4; ++ni) {
#pragma unroll
      for (int rq = 0; rq < 4; ++rq)
        Pp[(size_t)(row + rq) * NPAD + ni * 16 + r15] = acc[mi][ni][rq];
    }
  }
}

// ---------------------------------------------------------------------------
// TAIL MEGA-KERNEL (240 blocks, all co-resident, homemade grid barriers):
// phase0 reduce1(Y1->xt2) | bar | phase1 gemm2 | bar | phase2 reduce2(P->xt3)
// | bar | phase3 gemm3 | bar | phase4 reduce3(P->out).
// Replaces 5 dispatches + 4 launch gaps with intra-kernel barriers.
// ---------------------------------------------------------------------------
__global__ __launch_bounds__(256, 1)
void tail_fused(const float* __restrict__ Y1, const float* __restrict__ Omega,
                const float* __restrict__ b1, unsigned short* __restrict__ xt2,
                const float* __restrict__ w2, const float* __restrict__ b2,
                unsigned short* __restrict__ xt3,
                const float* __restrict__ w3, const float* __restrict__ b3,
                float* __restrict__ P, float* __restrict__ Yout,
                unsigned* __restrict__ bar)
{
  __shared__ SMg sm;
  const int bid = blockIdx.x;
  const int tid = threadIdx.x;

  // ---------- phase 0: reduce1 — xt2 = mix(elu(sum_e om*Y1 + om@b1)) ----------
  for (int b = bid; b < 256; b += NTAIL) {
    float om[8];
#pragma unroll
    for (int e = 0; e < 8; ++e) om[e] = Omega[b * 8 + e];
    const int swz = (b & 7) << 3;
    unsigned short* row = xt2 + (size_t)b * K2_N;
    for (int n = tid; n < HID_N; n += 256) {
      float acc = 0.f, bs = 0.f;
#pragma unroll
      for (int e = 0; e < 8; ++e) {
        const float ye = Y1[((size_t)e * 256 + b) * PN + n]
                       + Y1[((size_t)(8 + e) * 256 + b) * PN + n];
        acc += om[e] * ye;
        bs  += om[e] * b1[(size_t)e * HID_N + n];
      }
      const float y = acc + bs;
      const float a = (y > 0.f) ? y : expm1f(y);
#pragma unroll
      for (int e = 0; e < 8; ++e)
        row[(e * HID_N + n) ^ swz] = f2bf(om[e] * a);
    }
  }
  grid_bar(bar, NTAIL);

  // ---------- phase 1: gemm2 — P[sp] = xt2 @ w2 (12 nt x 20 sp) ----------
  gemm_body(sm, xt2, w2, P, K2_N, HID_N, 768, bid / 20, bid % 20);
  grid_bar(bar, 2 * NTAIL);

  // ---------- phase 2: reduce2 — xt3 = mix(elu(sumP + om@b2)) ----------
  for (int b = bid; b < 256; b += NTAIL) {
    float om[8];
#pragma unroll
    for (int e = 0; e < 8; ++e) om[e] = Omega[b * 8 + e];
    const int swz = (b & 7) << 3;
    unsigned short* row = xt3 + (size_t)b * K2_N;
    for (int n = tid; n < HID_N; n += 256) {
      float acc = 0.f;
#pragma unroll 4
      for (int s = 0; s < SPLITK; ++s) acc += P[((size_t)s * 256 + b) * 768 + n];
      float bs = 0.f;
#pragma unroll
      for (int e = 0; e < 8; ++e) bs += om[e] * b2[(size_t)e * HID_N + n];
      const float y = acc + bs;
      const float a = (y > 0.f) ? y : expm1f(y);
#pragma unroll
      for (int e = 0; e < 8; ++e)
        row[(e * HID_N + n) ^ swz] = f2bf(om[e] * a);
    }
  }
  grid_bar(bar, 3 * NTAIL);

  // ---------- phase 3: gemm3 — P[sp] = xt3 @ w3 (8 nt x 20 sp) ----------
  if (bid < 160) gemm_body(sm, xt3, w3, P, K2_N, 512, 512, bid / 20, bid % 20);
  grid_bar(bar, 4 * NTAIL);

  // ---------- phase 4: reduce3 — out = sumP + om@b3 ----------
  for (int b = bid; b < 256; b += NTAIL) {
    float om[8];
#pragma unroll
    for (int e = 0; e < 8; ++e) om[e] = Omega[b * 8 + e];
    for (int n = tid; n < 512; n += 256) {
      float acc = 0.f;
#pragma unroll 4
      for (int s = 0; s < SPLITK; ++s) acc += P[((size_t)s * 256 + b) * 512 + n];
      float bs = 0.f;
#pragma unroll
      for (int e = 0; e < 8; ++e) bs += om[e] * b3[(size_t)e * 512 + n];
      Yout[(size_t)b * 512 + n] = acc + bs;
    }
  }
}

// ---------------------------------------------------------------------------
extern "C" void kernel_launch(void* const* d_in, const int* in_sizes, int n_in,
                              void* d_out, int out_size, void* d_ws, size_t ws_size,
                              hipStream_t stream) {
  const float* X    = (const float*)d_in[0];
  const float* Wih0 = (const float*)d_in[1];
  const float* Whh0 = (const float*)d_in[2];
  const float* bih0 = (const float*)d_in[3];
  const float* bhh0 = (const float*)d_in[4];
  const float* Wih1 = (const float*)d_in[5];
  const float* Whh1 = (const float*)d_in[6];
  const float* bih1 = (const float*)d_in[7];
  const float* bhh1 = (const float*)d_in[8];
  const float* w1   = (const float*)d_in[9];
  const float* b1   = (const float*)d_in[10];
  const float* w2   = (const float*)d_in[11];
  const float* b2   = (const float*)d_in[12];
  const float* w3   = (const float*)d_in[13];
  const float* b3   = (const float*)d_in[14];

  char* ws = (char*)d_ws;
  float* Omega         = (float*)ws;                       // 8 KB
  unsigned* bar        = (unsigned*)(ws + 8192);           // 256 B (barrier)
  unsigned short* XmBf = (unsigned short*)(ws + 16384);    // 524,288
  unsigned short* xt2  = (unsigned short*)(ws + 540672);   // 3,080,192
  unsigned short* xt3  = (unsigned short*)(ws + 3620864);  // 3,080,192
  float* Y1            = (float*)(ws + 6701056);           // 12,582,912
  float* P             = (float*)(ws + 19283968);          // 15,728,640

  // Omega-free prep of bf16 Xm; zeroes the barrier counter
  xm_prep<<<dim3(4, 256), 256, 0, stream>>>(X, XmBf, bar);

  // GRU (16 blocks) runs CONCURRENTLY with the expert GEMM (192 blocks)
  fused_gru_gemm1<<<208, 256, 0, stream>>>(X, Wih0, Whh0, bih0, bhh0,
                                           Wih1, Whh1, bih1, bhh1,
                                           XmBf, w1, Y1, Omega);

  // whole tail in one dispatch with intra-kernel grid barriers
  tail_fused<<<NTAIL, 256, 0, stream>>>(Y1, Omega, b1, xt2, w2, b2, xt3,
                                        w3, b3, P, (float*)d_out, bar);
}

// Round 18
// 87.758 us; speedup vs baseline: 3.8363x; 3.8363x over previous
//
#include <hip/hip_runtime.h>
#include <cstdint>
#include <cstddef>

typedef __attribute__((ext_vector_type(8))) short short8;
typedef __attribute__((ext_vector_type(8))) unsigned short ushort8;
typedef __attribute__((ext_vector_type(4))) float f32x4;

#define AS1Q const __attribute__((address_space(1)))
#define AS3Q __attribute__((address_space(3)))

constexpr int T_N = 60, IN_N = 520, MOE_RAW_N = 512, MOE_IN_N = 992;
constexpr int HID_N = 752, E_N = 8;
constexpr int K2_N = 6016;            // 8*752
constexpr int KA_N = 1024;            // padded Xm row length (992 -> 1024)
constexpr int SPLITK2 = 10;           // tail GEMM split (R18: 20->10, halves P traffic)
constexpr int PN = 768;               // Y1 / P row pitch (layer-2 path)

static __device__ __forceinline__ unsigned short f2bf(float f) {
  unsigned int u = __float_as_uint(f);
  return (unsigned short)((u + 0x7fffu + ((u >> 16) & 1u)) >> 16);   // RNE
}
static __device__ __forceinline__ float sigf(float x) {
  return __fdividef(1.f, 1.f + __expf(-x));
}
static __device__ __forceinline__ float tanh_fast(float x) {
  return 2.f * __fdividef(1.f, 1.f + __expf(-2.f * x)) - 1.f;
}

// DPP row-rotate by R within the 16-lane row (pure VALU — no LDS pipe).
template<int R>
static __device__ __forceinline__ float rotf(float v) {
  return __int_as_float(__builtin_amdgcn_update_dpp(
      0, __float_as_int(v), 0x120 | R, 0xF, 0xF, true));
}
static __device__ __forceinline__ void rot8(float (&d)[8], float v) {
  d[0] = v;
  d[1] = rotf<1>(v); d[2] = rotf<2>(v); d[3] = rotf<3>(v);
  d[4] = rotf<4>(v); d[5] = rotf<5>(v); d[6] = rotf<6>(v); d[7] = rotf<7>(v);
}

// ---------------------------------------------------------------------------
// xm_prep: Xm_bf16[b][ (i ^ (b&7)<<3) ] = bf16(Xm[b,i]), rows padded to 1024.
// ---------------------------------------------------------------------------
__global__ __launch_bounds__(256)
void xm_prep(const float* __restrict__ X, unsigned short* __restrict__ XmBf)
{
  const int i = blockIdx.x * 256 + threadIdx.x;   // grid.x=4 -> 0..1023
  const int b = blockIdx.y;
  const float* Xb = X + (size_t)b * (T_N * IN_N);
  float v = 0.f;
  if (i < MOE_RAW_N) {
    v = Xb[(T_N - 1) * IN_N + i];
  } else if (i < MOE_IN_N) {
    const int q = i - MOE_RAW_N;
    v = Xb[(q >> 3) * IN_N + MOE_RAW_N + (q & 7)];
  }
  XmBf[(size_t)b * KA_N + (i ^ ((b & 7) << 3))] = f2bf(v);
}

// ---------------------------------------------------------------------------
// FUSED: GRU (blocks 0..15, LDS-resident weights — R11-proven) +
// expert-separated layer-1 GEMM (blocks 16..207). Verbatim from R11 (80.9us).
// ---------------------------------------------------------------------------
__global__ __launch_bounds__(256, 1)
void fused_gru_gemm1(const float* __restrict__ X,
                     const float* __restrict__ Wih0, const float* __restrict__ Whh0,
                     const float* __restrict__ bih0, const float* __restrict__ bhh0,
                     const float* __restrict__ Wih1, const float* __restrict__ Whh1,
                     const float* __restrict__ bih1, const float* __restrict__ bhh1,
                     const unsigned short* __restrict__ XmBf,
                     const float* __restrict__ w1,
                     float* __restrict__ Y1, float* __restrict__ Omega)
{
  __shared__ union SM {
    struct { unsigned short Al[2][256][64]; unsigned short Bl[2][64][64]; } g; // 80 KB
    struct { float xl[T_N][256]; float wl[12][8][8]; } r;                      // 63 KB
  } sm;

  const int tid  = threadIdx.x;
  const int lane = tid & 63;
  const int wave = tid >> 6;

  if (blockIdx.x < 16) {
    // ================= GRU branch: 16 samples per block =================
    const int j = tid & 7;
    const int b = blockIdx.x * 16 + (tid >> 4);

    const float* xsrc = X + (size_t)b * (T_N * IN_N) + MOE_RAW_N + j;
#pragma unroll
    for (int t = 0; t < T_N; ++t) {
      __builtin_amdgcn_global_load_lds((AS1Q unsigned int*)(xsrc + t * IN_N),
                                       (AS3Q unsigned int*)&sm.r.xl[t][wave * 64], 4, 0, 0);
    }

    const int got = __builtin_amdgcn_update_dpp(0, j, 0x121, 0xF, 0xF, true);
    const bool plus = (got == ((j + 1) & 7));

    // gather rotation-ordered weights into LDS: wl[mat*3+gate][j][r]
    if (tid < 64) {
      const int fj = tid >> 3, fr = tid & 7;
      const int idx = plus ? ((fj + fr) & 7) : ((fj - fr) & 7);
      const float* Wm[4] = {Wih0, Whh0, Wih1, Whh1};
#pragma unroll
      for (int mat = 0; mat < 4; ++mat)
#pragma unroll
        for (int gg = 0; gg < 3; ++gg)
          sm.r.wl[mat * 3 + gg][fj][fr] = Wm[mat][(gg * 8 + fj) * 8 + idx];
    }

    const float br0 = bih0[j] + bhh0[j], bz0 = bih0[8 + j] + bhh0[8 + j];
    const float bin0 = bih0[16 + j],     bhn0 = bhh0[16 + j];
    const float br1 = bih1[j] + bhh1[j], bz1 = bih1[8 + j] + bhh1[8 + j];
    const float bin1 = bih1[16 + j],     bhn1 = bhh1[16 + j];

    __syncthreads();   // xl (vmcnt) + wl (lgkmcnt) ready

    float h1 = 0.f, h2 = 0.f;
    float xcur = sm.r.xl[0][tid];

    auto dot8 = [&](int m, const float (&rv)[8], float& accA, float& accB) {
      const f32x4 w0 = *(const f32x4*)&sm.r.wl[m][j][0];
      const f32x4 w1v = *(const f32x4*)&sm.r.wl[m][j][4];
#pragma unroll
      for (int q = 0; q < 4; ++q) { accA += w0[q] * rv[q]; accB += w1v[q] * rv[4 + q]; }
    };

#pragma unroll 1
    for (int t = 0; t <= T_N; ++t) {   // 61 iterations (software pipeline)
      const float xnext = sm.r.xl[(t + 1 < T_N) ? t + 1 : T_N - 1][tid];

      float rx[8];  rot8(rx, xcur);
      float rh1[8]; rot8(rh1, h1);
      float rh2[8]; rot8(rh2, h2);

      float grA = br0, gzA = bz0, gnA = bin0, hnA = bhn0;
      float grB = 0.f, gzB = 0.f, gnB = 0.f, hnB = 0.f;
      dot8(0, rx, grA, grB); dot8(1, rx, gzA, gzB); dot8(2, rx, gnA, gnB);
      dot8(3, rh1, grA, grB); dot8(4, rh1, gzA, gzB); dot8(5, rh1, hnA, hnB);
      float h1n;
      {
        const float r0 = sigf(grA + grB), z0 = sigf(gzA + gzB);
        const float n0 = tanh_fast((gnA + gnB) + r0 * (hnA + hnB));
        h1n = (1.f - z0) * n0 + z0 * h1;
      }

      float grA1 = br1, gzA1 = bz1, gnA1 = bin1, hnA1 = bhn1;
      float grB1 = 0.f, gzB1 = 0.f, gnB1 = 0.f, hnB1 = 0.f;
      dot8(6, rh1, grA1, grB1); dot8(7, rh1, gzA1, gzB1); dot8(8, rh1, gnA1, gnB1);
      dot8(9, rh2, grA1, grB1); dot8(10, rh2, gzA1, gzB1); dot8(11, rh2, hnA1, hnB1);
      float h2n;
      {
        const float r1 = sigf(grA1 + grB1), z1 = sigf(gzA1 + gzB1);
        const float n1 = tanh_fast((gnA1 + gnB1) + r1 * (hnA1 + hnB1));
        h2n = (1.f - z1) * n1 + z1 * h2;
      }

      h1 = h1n;
      h2 = (t == 0) ? 0.f : h2n;
      xcur = xnext;
    }

    float rv[8]; rot8(rv, h2);
    float m = rv[0];
#pragma unroll
    for (int r = 1; r < 8; ++r) m = fmaxf(m, rv[r]);
    const float ej = __expf(h2 - m);
    float re[8]; rot8(re, ej);
    float sden = 0.f;
#pragma unroll
    for (int r = 0; r < 8; ++r) sden += re[r];
    if (!(tid & 8)) Omega[b * 8 + j] = __fdividef(ej, sden);
    return;
  }

  // ================= GEMM branch: Y1[sp][e] = Xm @ w1_e =================
  const int bid = blockIdx.x - 16;           // 0..191
  const int sp  = bid / 96;                  // 0..1
  const int rr0 = bid - sp * 96;
  const int e   = rr0 & 7;
  const int nt  = rr0 >> 3;                  // 0..11
  const int n0  = nt * 64;
  const int kt0 = sp * 8, kt1 = kt0 + 8;

  const int r15 = lane & 15, hi4 = lane >> 4, r7 = lane & 7;

  const unsigned short* Abase = XmBf + (size_t)(wave * 64 + (lane >> 3)) * KA_N + (lane & 7) * 8;
  const int bn = lane;
  const int kq = wave;
  const bool nvalid = (n0 + bn) < HID_N;
  const float* Bbase = w1 + ((size_t)e * MOE_IN_N + kq * 16) * HID_N + (n0 + bn);

  f32x4 acc[4][4];
  const f32x4 zero4 = {0.f, 0.f, 0.f, 0.f};
#pragma unroll
  for (int mi = 0; mi < 4; ++mi)
#pragma unroll
    for (int ni = 0; ni < 4; ++ni) acc[mi][ni] = zero4;

  auto stage = [&](int bufi, int kt) {
    const unsigned short* ga = Abase + kt * 64;
#pragma unroll
    for (int it = 0; it < 8; ++it) {
      __builtin_amdgcn_global_load_lds(
          (AS1Q unsigned int*)(ga + (size_t)it * 8 * KA_N),
          (AS3Q unsigned int*)&sm.g.Al[bufi][wave * 64 + it * 8][0],
          16, 0, 0);
    }
    const int kbase = kt * 64 + kq * 16;
    const float* gb = Bbase + (size_t)kt * 64 * HID_N;
    float v[16];
#pragma unroll
    for (int jj = 0; jj < 16; ++jj)
      v[jj] = (nvalid && (kbase + jj) < MOE_IN_N) ? gb[(size_t)jj * HID_N] : 0.f;
    ushort8 p0, p1;
#pragma unroll
    for (int jj = 0; jj < 8; ++jj) { p0[jj] = f2bf(v[jj]); p1[jj] = f2bf(v[jj + 8]); }
    const int sl0 = ((kq * 2) ^ (bn & 7)) * 8;
    const int sl1 = ((kq * 2 + 1) ^ (bn & 7)) * 8;
    *(ushort8*)&sm.g.Bl[bufi][bn][sl0] = p0;
    *(ushort8*)&sm.g.Bl[bufi][bn][sl1] = p1;
  };

  auto compute = [&](int bufi) {
#pragma unroll
    for (int ki = 0; ki < 2; ++ki) {
      const int ch = ((ki * 4 + hi4) ^ r7) * 8;
      short8 af[4], bfv[4];
#pragma unroll
      for (int mi = 0; mi < 4; ++mi)
        af[mi] = *(const short8*)&sm.g.Al[bufi][wave * 64 + mi * 16 + r15][ch];
#pragma unroll
      for (int ni = 0; ni < 4; ++ni)
        bfv[ni] = *(const short8*)&sm.g.Bl[bufi][ni * 16 + r15][ch];
#pragma unroll
      for (int mi = 0; mi < 4; ++mi)
#pragma unroll
        for (int ni = 0; ni < 4; ++ni)
          acc[mi][ni] = __builtin_amdgcn_mfma_f32_16x16x32_bf16(af[mi], bfv[ni], acc[mi][ni], 0, 0, 0);
    }
  };

  stage(0, kt0);
  __syncthreads();
  int buf = 0;
  for (int kt = kt0; kt < kt1; ++kt) {
    if (kt + 1 < kt1) stage(buf ^ 1, kt + 1);
    compute(buf);
    __syncthreads();
    buf ^= 1;
  }

  float* Pp = Y1 + ((size_t)(sp * 8 + e) * 256) * PN + n0;
#pragma unroll
  for (int mi = 0; mi < 4; ++mi) {
    const int row = wave * 64 + mi * 16 + hi4 * 4;
#pragma unroll
    for (int ni = 0; ni < 4; ++ni) {
#pragma unroll
      for (int rq = 0; rq < 4; ++rq)
        Pp[(size_t)(row + rq) * PN + ni * 16 + r15] = acc[mi][ni][rq];
    }
  }
}

// ---------------------------------------------------------------------------
// reduce1: a1 = elu( Sum_e Omega_e*(Y1[0][e]+Y1[1][e]) + Omega@b1 ) -> xt2.
// ---------------------------------------------------------------------------
__global__ __launch_bounds__(256)
void reduce1_mix(const float* __restrict__ Y1, const float* __restrict__ Omega,
                 const float* __restrict__ bias, unsigned short* __restrict__ xnext)
{
  const int n = blockIdx.x * 256 + threadIdx.x;
  const int b = blockIdx.y;
  if (n >= HID_N) return;
  float om[8];
#pragma unroll
  for (int e = 0; e < 8; ++e) om[e] = Omega[b * 8 + e];
  float acc = 0.f, bs = 0.f;
#pragma unroll
  for (int e = 0; e < 8; ++e) {
    const float ye = Y1[((size_t)e * 256 + b) * PN + n]
                   + Y1[((size_t)(8 + e) * 256 + b) * PN + n];
    acc += om[e] * ye;
    bs  += om[e] * bias[(size_t)e * HID_N + n];
  }
  const float y = acc + bs;
  const float a = (y > 0.f) ? y : expm1f(y);      // ELU
  const int swz = (b & 7) << 3;
  unsigned short* row = xnext + (size_t)b * K2_N;
#pragma unroll
  for (int e = 0; e < 8; ++e)
    row[(e * HID_N + n) ^ swz] = f2bf(om[e] * a);
}

// ---------------------------------------------------------------------------
// Split-K GEMM (R8/R11-proven slab form), SPLITK2=10.
// ---------------------------------------------------------------------------
__global__ __launch_bounds__(256)
void gemm_splitk(const unsigned short* __restrict__ A,
                 const float* __restrict__ Bw,
                 float* __restrict__ P,
                 int K, int N, int NPAD)
{
  __shared__ unsigned short Al[2][256][64];
  __shared__ unsigned short Bl[2][64][64];

  const int tid = threadIdx.x;
  const int lane = tid & 63;
  const int wave = tid >> 6;
  const int nt = blockIdx.x, sp = blockIdx.y;
  const int n0 = nt * 64;
  const int KT = K >> 6;
  const int kt0 = (KT * sp) / SPLITK2;
  const int kt1 = (KT * (sp + 1)) / SPLITK2;

  const int r15 = lane & 15, hi4 = lane >> 4, r7 = lane & 7;

  const unsigned short* Abase = A + (size_t)(wave * 64 + (lane >> 3)) * K + (lane & 7) * 8;
  const int bn = lane;
  const int kq = wave;
  const bool nvalid = (n0 + bn) < N;
  const float* Bbase = Bw + (size_t)(kq * 16) * N + (n0 + bn);

  f32x4 acc[4][4];
  const f32x4 zero4 = {0.f, 0.f, 0.f, 0.f};
#pragma unroll
  for (int mi = 0; mi < 4; ++mi)
#pragma unroll
    for (int ni = 0; ni < 4; ++ni) acc[mi][ni] = zero4;

  auto stage = [&](int bufi, int kt) {
    const unsigned short* ga = Abase + kt * 64;
#pragma unroll
    for (int it = 0; it < 8; ++it) {
      __builtin_amdgcn_global_load_lds(
          (AS1Q unsigned int*)(ga + (size_t)it * 8 * K),
          (AS3Q unsigned int*)&Al[bufi][wave * 64 + it * 8][0],
          16, 0, 0);
    }
    const float* gb = Bbase + (size_t)kt * 64 * N;
    float v[16];
#pragma unroll
    for (int jj = 0; jj < 16; ++jj) v[jj] = nvalid ? gb[(size_t)jj * N] : 0.f;
    ushort8 p0, p1;
#pragma unroll
    for (int jj = 0; jj < 8; ++jj) { p0[jj] = f2bf(v[jj]); p1[jj] = f2bf(v[jj + 8]); }
    const int sl0 = ((kq * 2) ^ (bn & 7)) * 8;
    const int sl1 = ((kq * 2 + 1) ^ (bn & 7)) * 8;
    *(ushort8*)&Bl[bufi][bn][sl0] = p0;
    *(ushort8*)&Bl[bufi][bn][sl1] = p1;
  };

  auto compute = [&](int bufi) {
#pragma unroll
    for (int ki = 0; ki < 2; ++ki) {
      const int ch = ((ki * 4 + hi4) ^ r7) * 8;
      short8 af[4], bfv[4];
#pragma unroll
      for (int mi = 0; mi < 4; ++mi)
        af[mi] = *(const short8*)&Al[bufi][wave * 64 + mi * 16 + r15][ch];
#pragma unroll
      for (int ni = 0; ni < 4; ++ni)
        bfv[ni] = *(const short8*)&Bl[bufi][ni * 16 + r15][ch];
#pragma unroll
      for (int mi = 0; mi < 4; ++mi)
#pragma unroll
        for (int ni = 0; ni < 4; ++ni)
          acc[mi][ni] = __builtin_amdgcn_mfma_f32_16x16x32_bf16(af[mi], bfv[ni], acc[mi][ni], 0, 0, 0);
    }
  };

  stage(0, kt0);
  __syncthreads();
  int buf = 0;
  for (int kt = kt0; kt < kt1; ++kt) {
    if (kt + 1 < kt1) stage(buf ^ 1, kt + 1);
    compute(buf);
    __syncthreads();
    buf ^= 1;
  }

  float* Pp = P + (size_t)sp * 256 * NPAD + n0;
#pragma unroll
  for (int mi = 0; mi < 4; ++mi) {
    const int row = wave * 64 + mi * 16 + hi4 * 4;
#pragma unroll
    for (int ni = 0; ni < 4; ++ni) {
#pragma unroll
      for (int rq = 0; rq < 4; ++rq)
        Pp[(size_t)(row + rq) * NPAD + ni * 16 + r15] = acc[mi][ni][rq];
    }
  }
}

// ---------------------------------------------------------------------------
// Reduce split-K partials + Omega-blended bias; ELU+mix -> xnext, or final out.
// ---------------------------------------------------------------------------
__global__ __launch_bounds__(256)
void reduce_mix_kernel(const float* __restrict__ P, const float* __restrict__ Omega,
                       const float* __restrict__ bias, unsigned short* __restrict__ xnext,
                       float* __restrict__ Yout, int N, int NPAD)
{
  const int n = blockIdx.x * 256 + threadIdx.x;
  const int b = blockIdx.y;
  if (n >= N) return;
  float acc = 0.f;
#pragma unroll 5
  for (int s = 0; s < SPLITK2; ++s) acc += P[((size_t)s * 256 + b) * NPAD + n];
  float om[8];
#pragma unroll
  for (int e = 0; e < 8; ++e) om[e] = Omega[b * 8 + e];
  float bs = 0.f;
#pragma unroll
  for (int e = 0; e < 8; ++e) bs += om[e] * bias[(size_t)e * N + n];
  float y = acc + bs;
  if (Yout) { Yout[(size_t)b * N + n] = y; return; }
  float a = (y > 0.f) ? y : expm1f(y);            // ELU
  const int swz = (b & 7) << 3;
  unsigned short* row = xnext + (size_t)b * K2_N;
#pragma unroll
  for (int e = 0; e < 8; ++e)
    row[(e * HID_N + n) ^ swz] = f2bf(om[e] * a);
}

// ---------------------------------------------------------------------------
extern "C" void kernel_launch(void* const* d_in, const int* in_sizes, int n_in,
                              void* d_out, int out_size, void* d_ws, size_t ws_size,
                              hipStream_t stream) {
  const float* X    = (const float*)d_in[0];
  const float* Wih0 = (const float*)d_in[1];
  const float* Whh0 = (const float*)d_in[2];
  const float* bih0 = (const float*)d_in[3];
  const float* bhh0 = (const float*)d_in[4];
  const float* Wih1 = (const float*)d_in[5];
  const float* Whh1 = (const float*)d_in[6];
  const float* bih1 = (const float*)d_in[7];
  const float* bhh1 = (const float*)d_in[8];
  const float* w1   = (const float*)d_in[9];
  const float* b1   = (const float*)d_in[10];
  const float* w2   = (const float*)d_in[11];
  const float* b2   = (const float*)d_in[12];
  const float* w3   = (const float*)d_in[13];
  const float* b3   = (const float*)d_in[14];

  char* ws = (char*)d_ws;
  float* Omega         = (float*)ws;                      // 8 KB
  unsigned short* XmBf = (unsigned short*)(ws + 8192);    // 524,288
  unsigned short* xt2  = (unsigned short*)(ws + 532480);  // 3,080,192
  unsigned short* xt3  = (unsigned short*)(ws + 3612672); // 3,080,192
  float* Y1            = (float*)(ws + 6692864);          // 12,582,912
  float* P             = (float*)(ws + 19275776);         // 10*256*768*4 = 7,864,320

  // Omega-free prep of bf16 Xm (swizzled, zero-padded to K=1024)
  xm_prep<<<dim3(4, 256), 256, 0, stream>>>(X, XmBf);

  // GRU (16 blocks) runs CONCURRENTLY with the expert GEMM (192 blocks)
  fused_gru_gemm1<<<208, 256, 0, stream>>>(X, Wih0, Whh0, bih0, bhh0,
                                           Wih1, Whh1, bih1, bhh1,
                                           XmBf, w1, Y1, Omega);

  // fold Omega + bias + ELU -> xt2
  reduce1_mix<<<dim3(3, 256), 256, 0, stream>>>(Y1, Omega, b1, xt2);

  // layer 2: 256 x 6016 @ 6016 x 752  (slab split-K, SPLITK2=10)
  gemm_splitk<<<dim3(12, SPLITK2), 256, 0, stream>>>(xt2, w2, P, K2_N, HID_N, 768);
  reduce_mix_kernel<<<dim3(3, 256), 256, 0, stream>>>(P, Omega, b2, xt3, nullptr, HID_N, 768);

  // layer 3: 256 x 6016 @ 6016 x 512  (slab split-K)
  gemm_splitk<<<dim3(8, SPLITK2), 256, 0, stream>>>(xt3, w3, P, K2_N, 512, 512);
  reduce_mix_kernel<<<dim3(2, 256), 256, 0, stream>>>(P, Omega, b3, nullptr, (float*)d_out, 512, 512);
}